// Round 19
// baseline (285.027 us; speedup 1.0000x reference)
//
#include <hip/hip_runtime.h>
#include <hip/hip_bf16.h>
#include <stdint.h>

#define E_ 768
#define H_ 768
#define C_ 9
#define M_TOTAL 32768
#define BM_ 64           // tokens per tile; tile is split into 2 half-blocks of 384 cols

typedef __attribute__((ext_vector_type(8))) __bf16 bf16x8;
typedef __attribute__((ext_vector_type(4))) float f32x4;
typedef __attribute__((ext_vector_type(4))) int i32x4;

static_assert(sizeof(bf16x8) == 16, "bf16x8 must be 16B");

__device__ __forceinline__ unsigned short f2bf(float f) {
    __hip_bfloat16 h = __float2bfloat16(f);
    return __builtin_bit_cast(unsigned short, h);
}

// ---------------------------------------------------------------------------
// Prep: W1 -> bf16 B-fragment cells (unchanged layout); W2 -> padded B-frag
// cells; loss zeroed. Blocks 769.. zero the 2MB logit workspace + flags
// (re-zeroed every launch -> correct under graph replay).
//   W1f[((ntile*24 + t)*64 + lane)*8 + j] = bf16(W1[k][n])
//     ntile=n>>4, t=k>>5, lane=(n&15)+16*((k>>3)&3), j=k&7
// ---------------------------------------------------------------------------
#define ZWORDS (524288 + 512)   // 32768*16 logit floats + 512 tile flags

__global__ void prep_kernel(const float* __restrict__ W1, const float* __restrict__ W2,
                            unsigned short* __restrict__ W1f, unsigned short* __restrict__ W2f,
                            float* __restrict__ loss_out, unsigned int* __restrict__ zws)
{
    int b = blockIdx.x;
    int n = threadIdx.x;
    if (b < 768) {
        int k = b;
        float v = W1[k * H_ + n];
        int ntile = n >> 4;
        int t = k >> 5;
        int lane = (n & 15) + 16 * ((k >> 3) & 3);
        int j = k & 7;
        W1f[((ntile * 24 + t) * 64 + lane) * 8 + j] = f2bf(v);
    } else if (b == 768) {
        for (int it = 0; it < 16; ++it) {
            int tid = it * 768 + n;
            int j    = tid & 7;
            int lane = (tid >> 3) & 63;
            int t    = tid >> 9;
            int cls  = lane & 15;
            int k = t * 32 + (lane >> 4) * 8 + j;
            W2f[tid] = (cls < C_) ? f2bf(W2[k * C_ + cls]) : (unsigned short)0;
        }
        if (n == 0) *loss_out = 0.0f;
    } else {
        size_t base = (size_t)(b - 769) * 1024;
        if (base + n < ZWORDS) zws[base + n] = 0u;
        if (n < 256 && base + 768 + n < ZWORDS) zws[base + 768 + n] = 0u;
    }
}

// ---------------------------------------------------------------------------
// Fused head kernel, round 12 (9th submit; broker timeouts, never ran):
// TWO co-resident blocks per CU at 1x total B traffic (R10 proved 2-domain
// concurrency = 1.71x per-k-step throughput; its only loss was doubled B
// work from BM=32. Fix: split the N dimension).
// Block = 512 thr (8 waves), covers 64 tokens x 384 h-cols (half = bid&1).
// Wave = 4mt x 3nt -> acc 48 AGPR + ~64 VGPR = 112 -> 2 blocks resident
// (16 waves/CU, INDEPENDENT barrier domains). Each block reads only its
// half of W1f -> total B traffic = 1x (604MB). Cost: hidden read 2x
// (+96MB HBM, headroom exists at 8% util).
// Epilogue (fusion preserved via split-K atomic finisher):
//   tanh -> Hsh(48KB, aliases A-dbuf) -> 12-step partial logit GEMM ->
//   atomicAdd partials into Lws[32768x16] (relaxed/agent) -> __syncthreads
//   (vmcnt(0) drain = adds device-visible) -> flags[tile] fetch_add(ACQ_REL):
//   the SECOND block re-reads combined logits (agent atomic loads, L1-bypass)
//   and does softmax + probs + loss. No spin -> deadlock-free, order-free.
// K-loop: R9 structure (A chunk-dbuf, af reg-dbuf, B reg dist-2, lgkm-only
// barriers, setprio around MFMA).
// ---------------------------------------------------------------------------
__launch_bounds__(512, 4)
__global__ void fused_head_kernel(const float* __restrict__ hidden,
                                  const unsigned short* __restrict__ W1f,
                                  const float* __restrict__ b1,
                                  const unsigned short* __restrict__ W2f,
                                  const float* __restrict__ b2,
                                  const int* __restrict__ labels,
                                  const int* __restrict__ epoch_p,
                                  float* __restrict__ probs,
                                  float* __restrict__ loss,
                                  float* __restrict__ Lws,
                                  int* __restrict__ flags)
{
    __shared__ unsigned short Ash[24576];   // 48KB. K-loop: A dbuf 2x16KB in [0,16384). Epilogue: Hsh all 24576.
    __shared__ int finFlag;

    const int tid  = threadIdx.x;
    const int w    = tid >> 6;     // wave 0..7
    const int lane = tid & 63;
    const int tile = blockIdx.x >> 1;
    const int half = blockIdx.x & 1;
    const int tok0 = tile * BM_;
    const int c16  = lane & 15;
    const int q    = lane >> 4;

    // ---- A staging: 4 slots/thread/chunk (64 rows x 32 float4 per chunk) ----
    const f32x4* hsrc = (const f32x4*)(hidden + (size_t)tok0 * E_);
    f32x4 rg[4];
    auto issue = [&](int c) {
        #pragma unroll
        for (int i = 0; i < 4; ++i) {
            int slot = i * 512 + tid;
            int tk = slot >> 5, fq = slot & 31;
            rg[i] = __builtin_nontemporal_load(hsrc + (size_t)tk * 192 + c * 32 + fq);
        }
    };
    auto stage = [&](int bsel) {
        unsigned short* bufp = &Ash[bsel * 8192];
        #pragma unroll
        for (int i = 0; i < 4; ++i) {
            int slot = i * 512 + tid;
            int tk = slot >> 5, fq = slot & 31;
            int t_l = fq >> 3, jj = (fq & 1) * 4, q2s = (fq >> 1) & 3;
            int lnf = (tk & 15) + 16 * q2s, mt = tk >> 4;
            ushort4 pk = { f2bf(rg[i][0]), f2bf(rg[i][1]), f2bf(rg[i][2]), f2bf(rg[i][3]) };
            *(ushort4*)(&bufp[((t_l * 4 + mt) * 64 + lnf) * 8 + jj]) = pk;
        }
    };

    issue(0);

    // ---- B registers: this block's half of W1f. cell0 = half*24 + w*3 ----
    const unsigned short* Wp = W1f + (size_t)(half * 24 + w * 3) * 24 * 512 + lane * 8;
    bf16x8 b0[3], b1v_[3];          // even/odd k-step B frags, dist-2 rotation
    #pragma unroll
    for (int i = 0; i < 3; ++i)
        b0[i] = __builtin_bit_cast(bf16x8, *(const i32x4*)(Wp + (i * 24 + 0) * 512));
    #pragma unroll
    for (int i = 0; i < 3; ++i)
        b1v_[i] = __builtin_bit_cast(bf16x8, *(const i32x4*)(Wp + (i * 24 + 1) * 512));

    const f32x4 zero4 = {0.0f, 0.0f, 0.0f, 0.0f};
    f32x4 acc[4][3];
    #pragma unroll
    for (int mt = 0; mt < 4; ++mt)
        #pragma unroll
        for (int nt = 0; nt < 3; ++nt) acc[mt][nt] = zero4;

    stage(0);
    asm volatile("s_waitcnt lgkmcnt(0)\ns_barrier" ::: "memory");

    // ---- af register double-buffer ----
    bf16x8 af[2][4];
    {
        const unsigned short* bufp = &Ash[0];
        #pragma unroll
        for (int mt = 0; mt < 4; ++mt)
            af[0][mt] = __builtin_bit_cast(bf16x8,
                *(const i32x4*)(&bufp[((0 * 4 + mt) * 64 + lane) * 8]));
    }

    // ---- K loop: 6 chunks x 4 k-steps ----
    #pragma unroll
    for (int c = 0; c < 6; ++c) {
        const unsigned short* bufp = &Ash[(c & 1) * 8192];
        if (c < 5) issue(c + 1);
        #pragma unroll
        for (int tl = 0; tl < 4; ++tl) {
            const int tt = 4 * c + tl;        // global k-step 0..23
            const int cur = tl & 1;
            if (tl < 3) {
                #pragma unroll
                for (int mt = 0; mt < 4; ++mt)
                    af[cur ^ 1][mt] = __builtin_bit_cast(bf16x8,
                        *(const i32x4*)(&bufp[(((tl + 1) * 4 + mt) * 64 + lane) * 8]));
            }
            __builtin_amdgcn_s_setprio(1);
            if ((tt & 1) == 0) {
                #pragma unroll
                for (int mt = 0; mt < 4; ++mt)
                    #pragma unroll
                    for (int nt = 0; nt < 3; ++nt)
                        acc[mt][nt] = __builtin_amdgcn_mfma_f32_16x16x32_bf16(
                            af[cur][mt], b0[nt], acc[mt][nt], 0, 0, 0);
            } else {
                #pragma unroll
                for (int mt = 0; mt < 4; ++mt)
                    #pragma unroll
                    for (int nt = 0; nt < 3; ++nt)
                        acc[mt][nt] = __builtin_amdgcn_mfma_f32_16x16x32_bf16(
                            af[cur][mt], b1v_[nt], acc[mt][nt], 0, 0, 0);
            }
            __builtin_amdgcn_s_setprio(0);
            if (tt + 2 < 24) {                // dist-2 refill of just-consumed parity
                if ((tt & 1) == 0) {
                    #pragma unroll
                    for (int i = 0; i < 3; ++i)
                        b0[i] = __builtin_bit_cast(bf16x8,
                            *(const i32x4*)(Wp + (i * 24 + tt + 2) * 512));
                } else {
                    #pragma unroll
                    for (int i = 0; i < 3; ++i)
                        b1v_[i] = __builtin_bit_cast(bf16x8,
                            *(const i32x4*)(Wp + (i * 24 + tt + 2) * 512));
                }
            }
            if (tl == 1 && c < 5) stage((c + 1) & 1);
        }
        asm volatile("s_waitcnt lgkmcnt(0)\ns_barrier" ::: "memory");
        if (c < 5) {
            const unsigned short* bufn = &Ash[((c + 1) & 1) * 8192];
            #pragma unroll
            for (int mt = 0; mt < 4; ++mt)
                af[0][mt] = __builtin_bit_cast(bf16x8,
                    *(const i32x4*)(&bufn[((0 * 4 + mt) * 64 + lane) * 8]));
        }
    }

    // ---- epilogue: all 8 waves tanh -> Hsh (48KB, local 384 cols) ----
    unsigned short* Hsh = &Ash[0];
    #pragma unroll
    for (int i = 0; i < 3; ++i) {
        int colL = w * 48 + i * 16 + c16;       // local h-col 0..383
        float b1b = b1[half * 384 + colL];      // global col
        int t2 = colL >> 5;
        int q2 = (colL >> 3) & 3;
        int j  = colL & 7;
        #pragma unroll
        for (int mt = 0; mt < 4; ++mt) {
            #pragma unroll
            for (int r = 0; r < 4; ++r) {
                float z = acc[mt][i][r] + b1b;
                // tanh(z) = 1 - 2/(exp(2z)+1), exp via native exp2
                float e = exp2f(z * 2.8853900817779268f);
                float th = 1.0f - 2.0f * __builtin_amdgcn_rcpf(e + 1.0f);
                int lanep = (q * 4 + r) + 16 * q2;
                Hsh[((t2 * 4 + mt) * 64 + lanep) * 8 + j] = f2bf(th);
            }
        }
    }
    asm volatile("s_waitcnt lgkmcnt(0)\ns_barrier" ::: "memory");

    // ---- partial logit GEMM (12 k-steps over this half's 384 cols) ----
    f32x4 logit = zero4;
    if (w < 4) {
        #pragma unroll
        for (int t2 = 0; t2 < 12; ++t2) {
            bf16x8 ha = __builtin_bit_cast(bf16x8, *(const i32x4*)(&Hsh[((t2 * 4 + w) * 64 + lane) * 8]));
            bf16x8 wb = __builtin_bit_cast(bf16x8, *(const i32x4*)(W2f + ((size_t)(half * 12 + t2) * 64 + lane) * 8));
            logit = __builtin_amdgcn_mfma_f32_16x16x32_bf16(ha, wb, logit, 0, 0, 0);
        }
        if (c16 < C_) {
            #pragma unroll
            for (int r = 0; r < 4; ++r) {
                int row = tok0 + w * 16 + q * 4 + r;
                __hip_atomic_fetch_add(&Lws[(size_t)row * 16 + c16], logit[r],
                                       __ATOMIC_RELAXED, __HIP_MEMORY_SCOPE_AGENT);
            }
        }
    }
    __syncthreads();   // vmcnt(0)+lgkmcnt(0) drain: our atomics are device-visible

    if (tid == 0) {
        finFlag = __hip_atomic_fetch_add(&flags[tile], 1,
                                         __ATOMIC_ACQ_REL, __HIP_MEMORY_SCOPE_AGENT);
    }
    __syncthreads();

    // ---- finisher (second arrival): combined softmax + probs + loss ----
    if (finFlag == 1 && w < 4) {
        const bool valid = (c16 < C_);
        const float b2v = valid ? b2[c16] : 0.0f;
        const int ep = epoch_p[0];
        float lsum = 0.0f;
        #pragma unroll
        for (int r = 0; r < 4; ++r) {
            int row = tok0 + w * 16 + q * 4 + r;
            float l = -3.0e38f;
            if (valid) {
                l = __hip_atomic_load(&Lws[(size_t)row * 16 + c16],
                                      __ATOMIC_RELAXED, __HIP_MEMORY_SCOPE_AGENT) + b2v;
            }
            float m = l;
            #pragma unroll
            for (int d = 1; d < 16; d <<= 1)
                m = fmaxf(m, __shfl_xor(m, d, 64));
            float e = valid ? exp2f((l - m) * 1.44269504f) : 0.0f;
            float s = e;
            #pragma unroll
            for (int d = 1; d < 16; d <<= 1)
                s += __shfl_xor(s, d, 64);
            float p = e / s;
            if (valid) __builtin_nontemporal_store(p, &probs[(size_t)row * C_ + c16]);
            int lab = labels[row];
            if (valid && lab == c16) {
                float wgt = (ep <= 2) ? 1.0f : ((p > 0.7f) ? 1.0f : 0.0f);
                if (wgt > 0.0f)
                    lsum += (1.0f - exp2f(0.7f * log2f(p))) * (1.0f / 0.7f);
            }
        }
        #pragma unroll
        for (int d = 1; d < 64; d <<= 1)
            lsum += __shfl_xor(lsum, d, 64);
        if (lane == 0) atomicAdd(loss, lsum);
    }
}

// ---------------------------------------------------------------------------
extern "C" void kernel_launch(void* const* d_in, const int* in_sizes, int n_in,
                              void* d_out, int out_size, void* d_ws, size_t ws_size,
                              hipStream_t stream)
{
    const float* hidden = (const float*)d_in[0];
    const float* W1     = (const float*)d_in[1];
    const float* b1     = (const float*)d_in[2];
    const float* W2     = (const float*)d_in[3];
    const float* b2     = (const float*)d_in[4];
    const int*   labels = (const int*)d_in[5];
    const int*   epoch  = (const int*)d_in[6];

    float* probs = (float*)d_out;                       // [32768 x 9]
    float* loss  = probs + (size_t)M_TOTAL * C_;        // scalar at the end

    unsigned short* W1f = (unsigned short*)d_ws;        // 589824 bf16 (ntile-major)
    unsigned short* W2f = W1f + 48 * 24 * 512;          // 12288 bf16
    float* Lws   = (float*)(W2f + 24 * 512);            // 524288 f32 logit partials (2MB)
    int*   flags = (int*)(Lws + 524288);                // 512 per-tile arrival counters

    // prep grid: 768 W1 rows + 1 (W2f/loss) + 520 zero-blocks (Lws+flags)
    prep_kernel<<<1289, 768, 0, stream>>>(W1, W2, W1f, W2f, loss, (unsigned int*)Lws);
    fused_head_kernel<<<(M_TOTAL / BM_) * 2, 512, 0, stream>>>(hidden, W1f, b1, W2f, b2,
                                                               labels, epoch, probs, loss,
                                                               Lws, flags);
}

// Round 21
// 252.638 us; speedup vs baseline: 1.1282x; 1.1282x over previous
//
#include <hip/hip_runtime.h>
#include <hip/hip_bf16.h>
#include <stdint.h>

#define E_ 768
#define H_ 768
#define C_ 9
#define M_TOTAL 32768
#define BM_ 64           // tokens per block (R13: back to R9 geometry, 1 block covers full N)

typedef __attribute__((ext_vector_type(8))) __bf16 bf16x8;
typedef __attribute__((ext_vector_type(4))) float f32x4;
typedef __attribute__((ext_vector_type(4))) int i32x4;

static_assert(sizeof(bf16x8) == 16, "bf16x8 must be 16B");

__device__ __forceinline__ unsigned short f2bf(float f) {
    __hip_bfloat16 h = __float2bfloat16(f);
    return __builtin_bit_cast(unsigned short, h);
}

// ---------------------------------------------------------------------------
// Prep v2 (R13): one thread per W1f CELL -> one coalesced 16-B store.
// Old prep wrote 2-B ushorts at 16-B stride (8x write-amplified scatter).
// Now: thread owns cell (ntile,t,lane), gathers 8 W1 floats (stride 768*4B;
// W1 is 2.25MB -> L2-resident) and stores 8 bf16 contiguously.
//   W1f[((ntile*24+t)*64+lane)*8 + j] = bf16(W1[k][n]),
//     k = t*32 + ((lane>>4)&3)*8 + j, n = ntile*16 + (lane&15)
// Block 288 does W2f (padded B-frag cells) + loss zero.
// ---------------------------------------------------------------------------
__global__ void prep_kernel(const float* __restrict__ W1, const float* __restrict__ W2,
                            unsigned short* __restrict__ W1f, unsigned short* __restrict__ W2f,
                            float* __restrict__ loss_out)
{
    int b = blockIdx.x;
    int n = threadIdx.x;
    if (b < 288) {
        int cell = b * 256 + n;            // 0..73727 = (ntile*24 + t)*64 + lane
        int lane = cell & 63;
        int t    = (cell >> 6) % 24;
        int nt   = cell / 1536;            // ntile 0..47
        int col  = nt * 16 + (lane & 15);
        int q2   = (lane >> 4) & 3;
        const float* src = W1 + (size_t)(t * 32 + q2 * 8) * H_ + col;
        int d[4];
        #pragma unroll
        for (int jj = 0; jj < 4; ++jj) {
            unsigned int lo = f2bf(src[(2 * jj)     * H_]);
            unsigned int hi = f2bf(src[(2 * jj + 1) * H_]);
            d[jj] = (int)(lo | (hi << 16));
        }
        i32x4 v = { d[0], d[1], d[2], d[3] };
        *(i32x4*)(W1f + (size_t)cell * 8) = v;   // 16-B aligned, coalesced
    } else {
        // b == 288: W2f -> padded B-frag cells (cols padded to 16), loss zero
        for (int it = 0; it < 48; ++it) {
            int tid = it * 256 + n;        // 0..12287
            int j    = tid & 7;
            int lane = (tid >> 3) & 63;
            int t    = tid >> 9;
            int cls  = lane & 15;
            int k = t * 32 + (lane >> 4) * 8 + j;
            W2f[tid] = (cls < C_) ? f2bf(W2[k * C_ + cls]) : (unsigned short)0;
        }
        if (n == 0) *loss_out = 0.0f;
    }
}

// ---------------------------------------------------------------------------
// Fused head kernel, round 13 (2nd submit; broker timeout, never ran):
// R9 structure + WAVE-PHASE STAGGER.
// R12 post-mortem: (a) atomic split-K finisher = ~150MB of uncached HBM RMW
// (WRITE 3.5->86MB) - dead end; (b) ERRATUM: R10's "1.71x concurrency" was a
// normalization artifact - per MFMA R10 was WORSE (24.2 vs 20.6 cy). The
// barrier-domain theory is struck. R9 (79.3us, MfmaUtil 17) is the base.
// New lever: K-accumulation COMMUTES, so wave w traverses each chunk's 4
// k-steps in rotated order kk=(p+(w&3))&3. At any instant the 16 waves sit
// at 4 different pipeline phases (B-load/A-read/MFMA) and read 4 different
// B cells -> cross-wave pipe overlap with no barrier or traffic change.
// Everything else identical to R9: A chunk-dbuf (2x16KB of 96KB Ash),
// af reg-dbuf, B reg dist-2 (two parity sets, refill slot s+2 in the wave's
// own schedule), lgkm-only barriers, setprio around MFMA, 16-wave epilogue
// tanh->Hsh(96KB) then waves 0-3: 24-step logit GEMM + softmax + loss.
// ---------------------------------------------------------------------------
__launch_bounds__(1024, 4)
__global__ void fused_head_kernel(const float* __restrict__ hidden,
                                  const unsigned short* __restrict__ W1f,
                                  const float* __restrict__ b1,
                                  const unsigned short* __restrict__ W2f,
                                  const float* __restrict__ b2,
                                  const int* __restrict__ labels,
                                  const int* __restrict__ epoch_p,
                                  float* __restrict__ probs,
                                  float* __restrict__ loss)
{
    __shared__ unsigned short Ash[24 * 4 * 512];   // 96 KB. K-loop: 2x16KB A-chunk dbuf. Epilogue: full Hsh.

    const int tid  = threadIdx.x;
    const int w    = tid >> 6;     // wave 0..15
    const int lane = tid & 63;
    const int w4   = w & 3;        // wave's k-phase rotation within each chunk
    const int tok0 = blockIdx.x * BM_;
    const int c16  = lane & 15;
    const int q    = lane >> 4;

    // ---- A staging geometry (R9): thread handles rows tkA and tkA+32 ----
    const f32x4* hsrc = (const f32x4*)(hidden + (size_t)tok0 * E_);
    const int tkA = tid >> 5;        // 0..31
    const int fq  = tid & 31;
    const int t_l = fq >> 3;
    const int jj  = (fq & 1) * 4;
    const int q2s = (fq >> 1) & 3;

    f32x4 rg0, rg1;
    auto issue = [&](int c) {
        rg0 = __builtin_nontemporal_load(hsrc + (size_t)tkA * 192 + c * 32 + fq);
        rg1 = __builtin_nontemporal_load(hsrc + (size_t)(tkA + 32) * 192 + c * 32 + fq);
    };
    auto stage = [&](int bsel) {
        unsigned short* bufp = &Ash[bsel * 8192];
        {
            int lnf = (tkA & 15) + 16 * q2s;
            int mt  = tkA >> 4;
            ushort4 pk = { f2bf(rg0[0]), f2bf(rg0[1]), f2bf(rg0[2]), f2bf(rg0[3]) };
            *(ushort4*)(&bufp[((t_l * 4 + mt) * 64 + lnf) * 8 + jj]) = pk;
        }
        {
            int tk = tkA + 32;
            int lnf = (tk & 15) + 16 * q2s;
            int mt  = tk >> 4;
            ushort4 pk = { f2bf(rg1[0]), f2bf(rg1[1]), f2bf(rg1[2]), f2bf(rg1[3]) };
            *(ushort4*)(&bufp[((t_l * 4 + mt) * 64 + lnf) * 8 + jj]) = pk;
        }
    };

    issue(0);

    // ---- B registers: dist-2 dbuf in the WAVE'S OWN rotated schedule ----
    // schedule slot s (0..23): k(s) = 4*(s>>2) + (((s&3) + w4) & 3)
    const unsigned short* Wp = W1f + (size_t)(w * 3 * 24) * 512 + lane * 8;
    bf16x8 bA[3], bB[3];             // even-slot / odd-slot sets
    {
        int g0 = w4;                 // k(0)
        int g1 = (1 + w4) & 3;       // k(1)
        #pragma unroll
        for (int i = 0; i < 3; ++i)
            bA[i] = __builtin_bit_cast(bf16x8, *(const i32x4*)(Wp + (i * 24 + g0) * 512));
        #pragma unroll
        for (int i = 0; i < 3; ++i)
            bB[i] = __builtin_bit_cast(bf16x8, *(const i32x4*)(Wp + (i * 24 + g1) * 512));
    }

    const f32x4 zero4 = {0.0f, 0.0f, 0.0f, 0.0f};
    f32x4 acc[4][3];
    #pragma unroll
    for (int mt = 0; mt < 4; ++mt)
        #pragma unroll
        for (int nt = 0; nt < 3; ++nt) acc[mt][nt] = zero4;

    stage(0);
    asm volatile("s_waitcnt lgkmcnt(0)\ns_barrier" ::: "memory");

    // ---- af register double-buffer: prologue = chunk 0, wave's position 0 (kk=w4) ----
    bf16x8 af[2][4];
    {
        const unsigned short* bufp = &Ash[0];
        #pragma unroll
        for (int mt = 0; mt < 4; ++mt)
            af[0][mt] = __builtin_bit_cast(bf16x8,
                *(const i32x4*)(&bufp[((w4 * 4 + mt) * 64 + lane) * 8]));
    }

    // ---- K loop: 6 chunks x 4 positions; per-wave rotated k order ----
    #pragma unroll
    for (int c = 0; c < 6; ++c) {
        const unsigned short* bufp = &Ash[(c & 1) * 8192];
        if (c < 5) issue(c + 1);
        #pragma unroll
        for (int p = 0; p < 4; ++p) {
            const int cur = p & 1;
            if (p < 3) {                       // prefetch wave's next position
                int kkn = (p + 1 + w4) & 3;
                #pragma unroll
                for (int mt = 0; mt < 4; ++mt)
                    af[cur ^ 1][mt] = __builtin_bit_cast(bf16x8,
                        *(const i32x4*)(&bufp[((kkn * 4 + mt) * 64 + lane) * 8]));
            }
            __builtin_amdgcn_s_setprio(1);
            if (cur == 0) {
                #pragma unroll
                for (int mt = 0; mt < 4; ++mt)
                    #pragma unroll
                    for (int nt = 0; nt < 3; ++nt)
                        acc[mt][nt] = __builtin_amdgcn_mfma_f32_16x16x32_bf16(
                            af[cur][mt], bA[nt], acc[mt][nt], 0, 0, 0);
            } else {
                #pragma unroll
                for (int mt = 0; mt < 4; ++mt)
                    #pragma unroll
                    for (int nt = 0; nt < 3; ++nt)
                        acc[mt][nt] = __builtin_amdgcn_mfma_f32_16x16x32_bf16(
                            af[cur][mt], bB[nt], acc[mt][nt], 0, 0, 0);
            }
            __builtin_amdgcn_s_setprio(0);
            if (4 * c + p + 2 < 24) {          // refill this parity: slot s+2 of wave's schedule
                const int gc = c + ((p + 2) >> 2);          // compile-time chunk
                int g = 4 * gc + ((((p + 2) & 3) + w4) & 3);
                if (cur == 0) {
                    #pragma unroll
                    for (int i = 0; i < 3; ++i)
                        bA[i] = __builtin_bit_cast(bf16x8,
                            *(const i32x4*)(Wp + (i * 24 + g) * 512));
                } else {
                    #pragma unroll
                    for (int i = 0; i < 3; ++i)
                        bB[i] = __builtin_bit_cast(bf16x8,
                            *(const i32x4*)(Wp + (i * 24 + g) * 512));
                }
            }
            if (p == 1 && c < 5) stage((c + 1) & 1);
        }
        // lgkm-only barrier: next chunk's ds_writes visible; B loads stay in flight
        asm volatile("s_waitcnt lgkmcnt(0)\ns_barrier" ::: "memory");
        if (c < 5) {                           // next chunk, wave's position 0 (kk=w4)
            const unsigned short* bufn = &Ash[((c + 1) & 1) * 8192];
            #pragma unroll
            for (int mt = 0; mt < 4; ++mt)
                af[0][mt] = __builtin_bit_cast(bf16x8,
                    *(const i32x4*)(&bufn[((w4 * 4 + mt) * 64 + lane) * 8]));
        }
    }

    // ---- epilogue: all 16 waves write tanh into full Hsh (96 KB) ----
    unsigned short* Hsh = &Ash[0];
    #pragma unroll
    for (int i = 0; i < 3; ++i) {
        int col = w * 48 + i * 16 + c16;        // global h-column 0..767
        float b1b = b1[col];
        int t2 = col >> 5;
        int q2 = (col >> 3) & 3;
        int j  = col & 7;
        #pragma unroll
        for (int mt = 0; mt < 4; ++mt) {
            #pragma unroll
            for (int r = 0; r < 4; ++r) {
                float z = acc[mt][i][r] + b1b;
                // tanh(z) = 1 - 2/(exp(2z)+1), exp via native exp2
                float e = exp2f(z * 2.8853900817779268f);
                float th = 1.0f - 2.0f * __builtin_amdgcn_rcpf(e + 1.0f);
                int lanep = (q * 4 + r) + 16 * q2;
                Hsh[((t2 * 4 + mt) * 64 + lanep) * 8 + j] = f2bf(th);
            }
        }
    }
    asm volatile("s_waitcnt lgkmcnt(0)\ns_barrier" ::: "memory");

    // ---- logit GEMM (24 straight k-steps, waves 0-3) + softmax + loss ----
    if (w < 4) {
        f32x4 logit = zero4;
        #pragma unroll
        for (int t2 = 0; t2 < 24; ++t2) {
            bf16x8 ha = __builtin_bit_cast(bf16x8, *(const i32x4*)(&Hsh[((t2 * 4 + w) * 64 + lane) * 8]));
            bf16x8 wb = __builtin_bit_cast(bf16x8, *(const i32x4*)(W2f + ((size_t)t2 * 64 + lane) * 8));
            logit = __builtin_amdgcn_mfma_f32_16x16x32_bf16(ha, wb, logit, 0, 0, 0);
        }

        const bool valid = (c16 < C_);
        const float b2v = valid ? b2[c16] : 0.0f;
        const int ep = epoch_p[0];
        float lsum = 0.0f;
        #pragma unroll
        for (int r = 0; r < 4; ++r) {
            float l = valid ? (logit[r] + b2v) : -3.0e38f;
            float m = l;
            #pragma unroll
            for (int d = 1; d < 16; d <<= 1)
                m = fmaxf(m, __shfl_xor(m, d, 64));
            float e = valid ? exp2f((l - m) * 1.44269504f) : 0.0f;
            float s = e;
            #pragma unroll
            for (int d = 1; d < 16; d <<= 1)
                s += __shfl_xor(s, d, 64);
            float p = e / s;
            int row = tok0 + w * 16 + q * 4 + r;
            if (valid) __builtin_nontemporal_store(p, &probs[(size_t)row * C_ + c16]);
            int lab = labels[row];
            if (valid && lab == c16) {
                float wgt = (ep <= 2) ? 1.0f : ((p > 0.7f) ? 1.0f : 0.0f);
                if (wgt > 0.0f)
                    lsum += (1.0f - exp2f(0.7f * log2f(p))) * (1.0f / 0.7f);
            }
        }
        #pragma unroll
        for (int d = 1; d < 64; d <<= 1)
            lsum += __shfl_xor(lsum, d, 64);
        if (lane == 0) atomicAdd(loss, lsum);
    }
}

// ---------------------------------------------------------------------------
extern "C" void kernel_launch(void* const* d_in, const int* in_sizes, int n_in,
                              void* d_out, int out_size, void* d_ws, size_t ws_size,
                              hipStream_t stream)
{
    const float* hidden = (const float*)d_in[0];
    const float* W1     = (const float*)d_in[1];
    const float* b1     = (const float*)d_in[2];
    const float* W2     = (const float*)d_in[3];
    const float* b2     = (const float*)d_in[4];
    const int*   labels = (const int*)d_in[5];
    const int*   epoch  = (const int*)d_in[6];

    float* probs = (float*)d_out;                       // [32768 x 9]
    float* loss  = probs + (size_t)M_TOTAL * C_;        // scalar at the end

    unsigned short* W1f = (unsigned short*)d_ws;        // 589824 bf16 (ntile-major)
    unsigned short* W2f = W1f + 48 * 24 * 512;          // 12288 bf16

    prep_kernel<<<289, 256, 0, stream>>>(W1, W2, W1f, W2f, loss);
    fused_head_kernel<<<M_TOTAL / BM_, 1024, 0, stream>>>(hidden, W1f, b1, W2f, b2,
                                                          labels, epoch, probs, loss);
}